// Round 6
// baseline (514.138 us; speedup 1.0000x reference)
//
#include <hip/hip_runtime.h>
#include <hip/hip_bf16.h>

// DotProductAttention: B=4, N=4096, E=1024, D=256. f32 in/out.
// Pipeline: cast/prep -> QKV GEMM (z=3) -> VT GEMM -> k_score (packed
// lower-tri P~, rowsum l) -> k_pv (O = P~ @ V / l).
// R7: k_score enumerates only the 528 lower-tri tiles/b.
// R8/R9: coset-balanced k_pv: MfmaUtil stuck 24% (timeline, not sum).
// R10 FAILED: split-k atomics -> WRITE 3x. Reverted.
// R11: XCD-grouped k_pv decode (FETCH 310->152MB) + dbuf vmcnt(4). 331us.
// R12 FAILED both: LDS swizzle null (SQ_LDS_BANK_CONFLICT bit-identical:
// b128 over 32 banks is INHERENTLY 8-way aliased, 16 extra cyc/read);
// DEPTH=3 cut residency 4->3 blocks/CU (112->143us). Reverted.
// R13: k_pv and k_score go LDS-FREE. The MFMA A/B fragment (16 contiguous
// bytes along K) is directly loadable from global: P/VT/Q/K rows are all
// K-contiguous, and a wave's 64 fragment addrs tile whole 64B lines (4
// lanes/line) -> coalesced. LDS staging only bought 2x reuse (wave mirror
// pairs), now served by L1/L2. No barriers, no vmcnt lockstep: 16
// free-running waves/CU + compiler reg-pipelining hide VMEM latency.
// QKV/VT GEMMs keep the R11 LDS path (real K-reuse there).

typedef __hip_bfloat16 bf16;
typedef __bf16 bf16x4 __attribute__((ext_vector_type(4)));
typedef __bf16 bf16x8 __attribute__((ext_vector_type(8)));
typedef float f32x4 __attribute__((ext_vector_type(4)));

#define BK 32
#define HALF_BYTES 8192  // 128*BK*2 bytes per LDS buffer half

__device__ __forceinline__ void gload_lds16(const bf16* g, bf16* l) {
    __builtin_amdgcn_global_load_lds(
        (const __attribute__((address_space(1))) unsigned int*)g,
        (__attribute__((address_space(3))) unsigned int*)l, 16, 0, 0);
}

__device__ __forceinline__ void zero_acc(f32x4 acc[4][4]) {
#pragma unroll
    for (int mi = 0; mi < 4; ++mi)
#pragma unroll
        for (int ni = 0; ni < 4; ++ni) {
            f32x4 zf = {0.f, 0.f, 0.f, 0.f};
            acc[mi][ni] = zf;
        }
}

// ---------- LDS-free tile: fragments straight from global ------------------
// acc += A[128 x K] * BT[128 x K]^T, fragments loaded per-lane from global.
// Lane (quad=lane>>4, r=lane&15): A frag mi = A[(mrow+mi*16)]
// [it*32+quad*8 .. +7] -- 16B, 16 lanes x 4 quads tile 16 rows x 64B lines.
__device__ __forceinline__ void mm_tile_direct(const bf16* __restrict__ Ablk,
                                               const bf16* __restrict__ Bblk,
                                               int lda, int ldb, int kiters,
                                               f32x4 acc[4][4]) {
    const int tid  = threadIdx.x;
    const int wave = tid >> 6;
    const int lane = tid & 63;
    const int waveM = wave >> 1, waveN = wave & 1;
    const int mrow = waveM * 64 + (lane & 15);
    const int nrow = waveN * 64 + (lane & 15);
    const int koff = (lane >> 4) * 8;

    const bf16* pa0 = Ablk + (size_t)(mrow +  0) * lda + koff;
    const bf16* pa1 = Ablk + (size_t)(mrow + 16) * lda + koff;
    const bf16* pa2 = Ablk + (size_t)(mrow + 32) * lda + koff;
    const bf16* pa3 = Ablk + (size_t)(mrow + 48) * lda + koff;
    const bf16* pb0 = Bblk + (size_t)(nrow +  0) * ldb + koff;
    const bf16* pb1 = Bblk + (size_t)(nrow + 16) * ldb + koff;
    const bf16* pb2 = Bblk + (size_t)(nrow + 32) * ldb + koff;
    const bf16* pb3 = Bblk + (size_t)(nrow + 48) * ldb + koff;

#pragma unroll 2
    for (int it = 0; it < kiters; ++it) {
        bf16x8 af[4], bfr[4];
        af[0] = *(const bf16x8*)pa0; pa0 += BK;
        af[1] = *(const bf16x8*)pa1; pa1 += BK;
        af[2] = *(const bf16x8*)pa2; pa2 += BK;
        af[3] = *(const bf16x8*)pa3; pa3 += BK;
        bfr[0] = *(const bf16x8*)pb0; pb0 += BK;
        bfr[1] = *(const bf16x8*)pb1; pb1 += BK;
        bfr[2] = *(const bf16x8*)pb2; pb2 += BK;
        bfr[3] = *(const bf16x8*)pb3; pb3 += BK;
#pragma unroll
        for (int mi = 0; mi < 4; ++mi)
#pragma unroll
            for (int ni = 0; ni < 4; ++ni)
                acc[mi][ni] = __builtin_amdgcn_mfma_f32_16x16x32_bf16(
                    af[mi], bfr[ni], acc[mi][ni], 0, 0, 0);
    }
}

// ---------- LDS-staged tile (R11): used by the dense GEMMs -----------------
__device__ __forceinline__ void mm_tile(const bf16* __restrict__ Ablk,
                                        const bf16* __restrict__ Bblk,
                                        int lda, int ldb, int kiters,
                                        bf16* As, bf16* Bs, f32x4 acc[4][4]) {
    const int tid  = threadIdx.x;
    const int wave = tid >> 6;
    const int lane = tid & 63;

    const int F0 = wave * 2048 + lane * 16;  // byte offset; 4 waves cover 8KB
    const int F1 = F0 + 1024;
    const int r0 = F0 >> 6, c0 = (F0 & 63) >> 1;  // 64B (=32 bf16) per row
    const int r1 = F1 >> 6, c1 = (F1 & 63) >> 1;
    const bf16* ga0 = Ablk + (size_t)r0 * lda + c0;
    const bf16* ga1 = Ablk + (size_t)r1 * lda + c1;
    const bf16* gb0 = Bblk + (size_t)r0 * ldb + c0;
    const bf16* gb1 = Bblk + (size_t)r1 * ldb + c1;

    const int waveM = wave >> 1, waveN = wave & 1;
    const int mrow = waveM * 64 + (lane & 15);
    const int nrow = waveN * 64 + (lane & 15);
    const int koff = (lane >> 4) * 8;

#define STAGE_TO(buf)                                                        \
    {                                                                        \
        char* Ad = (char*)As + (buf) * HALF_BYTES;                           \
        char* Bd = (char*)Bs + (buf) * HALF_BYTES;                           \
        gload_lds16(ga0, (bf16*)(Ad + F0));                                  \
        gload_lds16(ga1, (bf16*)(Ad + F1));                                  \
        gload_lds16(gb0, (bf16*)(Bd + F0));                                  \
        gload_lds16(gb1, (bf16*)(Bd + F1));                                  \
        ga0 += BK; ga1 += BK; gb0 += BK; gb1 += BK;                          \
    }

    STAGE_TO(0);
    int cur = 0;
    for (int it = 0; it < kiters - 1; ++it) {
        const int nxt = cur ^ 1;
        STAGE_TO(nxt);

        __builtin_amdgcn_sched_barrier(0);
        asm volatile("s_waitcnt vmcnt(4)" ::: "memory");
        __builtin_amdgcn_sched_barrier(0);
        __builtin_amdgcn_s_barrier();
        __builtin_amdgcn_sched_barrier(0);

        {
            const bf16* Ar = (const bf16*)((const char*)As + cur * HALF_BYTES);
            const bf16* Br = (const bf16*)((const char*)Bs + cur * HALF_BYTES);
            bf16x8 af[4], bfr[4];
#pragma unroll
            for (int mi = 0; mi < 4; ++mi)
                af[mi] = *(const bf16x8*)(Ar + (mrow + mi * 16) * BK + koff);
#pragma unroll
            for (int ni = 0; ni < 4; ++ni)
                bfr[ni] = *(const bf16x8*)(Br + (nrow + ni * 16) * BK + koff);
#pragma unroll
            for (int mi = 0; mi < 4; ++mi)
#pragma unroll
                for (int ni = 0; ni < 4; ++ni)
                    acc[mi][ni] = __builtin_amdgcn_mfma_f32_16x16x32_bf16(
                        af[mi], bfr[ni], acc[mi][ni], 0, 0, 0);
        }

        __builtin_amdgcn_sched_barrier(0);
        asm volatile("s_waitcnt lgkmcnt(0)" ::: "memory");
        __builtin_amdgcn_sched_barrier(0);
        __builtin_amdgcn_s_barrier();
        __builtin_amdgcn_sched_barrier(0);
        cur = nxt;
    }

    __builtin_amdgcn_sched_barrier(0);
    asm volatile("s_waitcnt vmcnt(0)" ::: "memory");
    __builtin_amdgcn_sched_barrier(0);
    __builtin_amdgcn_s_barrier();
    __builtin_amdgcn_sched_barrier(0);
    {
        const bf16* Ar = (const bf16*)((const char*)As + cur * HALF_BYTES);
        const bf16* Br = (const bf16*)((const char*)Bs + cur * HALF_BYTES);
        bf16x8 af[4], bfr[4];
#pragma unroll
        for (int mi = 0; mi < 4; ++mi)
            af[mi] = *(const bf16x8*)(Ar + (mrow + mi * 16) * BK + koff);
#pragma unroll
        for (int ni = 0; ni < 4; ++ni)
            bfr[ni] = *(const bf16x8*)(Br + (nrow + ni * 16) * BK + koff);
#pragma unroll
        for (int mi = 0; mi < 4; ++mi)
#pragma unroll
            for (int ni = 0; ni < 4; ++ni)
                acc[mi][ni] = __builtin_amdgcn_mfma_f32_16x16x32_bf16(
                    af[mi], bfr[ni], acc[mi][ni], 0, 0, 0);
    }
#undef STAGE_TO
}

// ---------------- plain GEMM: C[m][n] = A*BT^T, bf16 store -----------------
__global__ __launch_bounds__(256, 2) void k_gemm_plain(
    const bf16* __restrict__ A, long long aBatch,
    const bf16* __restrict__ BT, long long bBatch,
    bf16* __restrict__ C, long long cBatch,
    int lda, int ldb, int ldc, int kiters) {
    __shared__ __align__(16) bf16 As[2 * 128 * BK];
    __shared__ __align__(16) bf16 Bs[2 * 128 * BK];
    const int nBase = blockIdx.x * 128;
    const int mBase = blockIdx.y * 128;
    const int z = blockIdx.z;
    const bf16* Ab = A + (size_t)z * aBatch + (size_t)mBase * lda;
    const bf16* Bb = BT + (size_t)z * bBatch + (size_t)nBase * ldb;

    f32x4 acc[4][4];
    zero_acc(acc);
    mm_tile(Ab, Bb, lda, ldb, kiters, As, Bs, acc);

    const int tid = threadIdx.x, wave = tid >> 6, lane = tid & 63;
    const int waveM = wave >> 1, waveN = wave & 1;
    const int quad = lane >> 4, cno = lane & 15;
    bf16* Cb = C + (size_t)z * cBatch;
#pragma unroll
    for (int mi = 0; mi < 4; ++mi) {
        int row0 = mBase + waveM * 64 + mi * 16 + quad * 4;
#pragma unroll
        for (int ni = 0; ni < 4; ++ni) {
            int col = nBase + waveN * 64 + ni * 16 + cno;
#pragma unroll
            for (int r = 0; r < 4; ++r)
                Cb[(size_t)(row0 + r) * ldc + col] = __float2bfloat16(acc[mi][ni][r]);
        }
    }
}

// ---------------- score: packed P~ = exp(mask(Q K^T / 16)) -----------------
// LDS-free: Q/K fragments straight from global (both L2/L3-warm, 8MB each).
// Only the 528 lower-tri tiles per batch are launched; flat index f decodes
// to (qt, kt). P packed per batch: block-row qt starts at element
// 16384*qt*(qt+1)/2, rows have pitch (qt+1)*128. Row sums -> lsum atomics.
#define P_BATCH 8650752ll  // 528 * 16384 elements per batch
__global__ __launch_bounds__(256, 4) void k_score(
    const bf16* __restrict__ Qm, const bf16* __restrict__ Km,
    bf16* __restrict__ P, float* __restrict__ lsum) {
    const int f = blockIdx.x, b = blockIdx.z;
    // decode f -> (qt, kt): qt = floor((sqrt(8f+1)-1)/2), kt = f - tri(qt)
    int qt = (int)((sqrtf(8.f * (float)f + 1.f) - 1.f) * 0.5f);
    while ((qt + 1) * (qt + 2) / 2 <= f) ++qt;
    while (qt * (qt + 1) / 2 > f) --qt;
    const int kt = f - qt * (qt + 1) / 2;

    const bf16* Ab = Qm + ((size_t)b * 4096 + (size_t)qt * 128) * 256;
    const bf16* Bb = Km + ((size_t)b * 4096 + (size_t)kt * 128) * 256;

    f32x4 acc[4][4];
    zero_acc(acc);
    mm_tile_direct(Ab, Bb, 256, 256, 256 / BK, acc);

    const int tid = threadIdx.x, wave = tid >> 6, lane = tid & 63;
    const int waveM = wave >> 1, waveN = wave & 1;
    const int quad = lane >> 4, cno = lane & 15;
    const int pitch = (qt + 1) * 128;
    bf16* Pb = P + b * P_BATCH + (size_t)16384 * (qt * (qt + 1) / 2);
    float* lb = lsum + b * 4096;
#pragma unroll
    for (int mi = 0; mi < 4; ++mi) {
        const int lq0 = waveM * 64 + mi * 16 + quad * 4;
        float rs[4] = {0.f, 0.f, 0.f, 0.f};
#pragma unroll
        for (int ni = 0; ni < 4; ++ni) {
            const int cn = waveN * 64 + ni * 16 + cno;
            const int gk = kt * 128 + cn;
#pragma unroll
            for (int r = 0; r < 4; ++r) {
                const int gq = qt * 128 + lq0 + r;
                float s = acc[mi][ni][r] * 0.0625f;  // 1/sqrt(256)
                // ref quirk: masked OR exactly-zero score -> exp = 0
                float p = (gk <= gq && s != 0.0f) ? __expf(s) : 0.0f;
                bf16 pb = __float2bfloat16(p);
                Pb[(size_t)(lq0 + r) * pitch + gk] = pb;
                rs[r] += __bfloat162float(pb);  // sum what PV multiplies
            }
        }
#pragma unroll
        for (int r = 0; r < 4; ++r) {
            float v = rs[r];
            v += __shfl_xor(v, 1);
            v += __shfl_xor(v, 2);
            v += __shfl_xor(v, 4);
            v += __shfl_xor(v, 8);
            if (cno == 0) atomicAdd(&lb[qt * 128 + lq0 + r], v);
        }
    }
}

// --------------- PV GEMM, LDS-free, XCD-grouped + CU-coset balanced --------
// l = dv*128 + (b*32 + u): the 8 dv-siblings of a (qt,b) share l%8 -> same
// XCD under round-robin dispatch -> shared P-tile fetched once per XCD L2.
// qt from x=u&7, slot m=((u>>3)+(dv>>1))&3 via {x, 15-x, 16+x, 31-x}: the 4
// blocks per CU coset sum qt=62 -> 264 k-steps/CU. No LDS, no barriers:
// fragments straight from global, waves free-run, compiler reg-pipelines.
__global__ __launch_bounds__(256, 4) void k_pv(
    const bf16* __restrict__ P, const bf16* __restrict__ VT,
    const float* __restrict__ lsum, float* __restrict__ Out) {
    const int l = blockIdx.x;        // 0..1023
    const int dv = l >> 7;           // 0..7 (outer -> XCD-invariant)
    const int w = l & 127;
    const int b = w >> 5;            // 0..3
    const int u = w & 31;            // 0..31
    const int x = u & 7;             // XCD slot (= l%8)
    const int k = u >> 3;            // 0..3
    const int m = (k + (dv >> 1)) & 3;
    const int qt = (m == 0) ? x : (m == 1) ? (15 - x)
                 : (m == 2) ? (16 + x) : (31 - x);
    const int dvBase = dv * 128;
    const int tid = threadIdx.x, wave = tid >> 6, lane = tid & 63;
    const int waveM = wave >> 1, waveN = wave & 1;
    const int quad = lane >> 4, cno = lane & 15;

    const bf16* Bb = VT + ((size_t)b * 1024 + dvBase) * 4096;
    float* Ob = Out + (size_t)b * 4096 * 1024;
    const float* lb = lsum + b * 4096;

    const int pitch = (qt + 1) * 128;
    const bf16* Ab = P + b * P_BATCH + (size_t)16384 * (qt * (qt + 1) / 2);

    f32x4 acc[4][4];
    zero_acc(acc);
    mm_tile_direct(Ab, Bb, pitch, 4096, (qt + 1) * (128 / BK), acc);

#pragma unroll
    for (int mi = 0; mi < 4; ++mi) {
        const int lq0 = waveM * 64 + mi * 16 + quad * 4;
#pragma unroll
        for (int r = 0; r < 4; ++r) {
            const int gq = qt * 128 + lq0 + r;
            const float inv = 1.0f / lb[gq];
#pragma unroll
            for (int ni = 0; ni < 4; ++ni) {
                const int col = dvBase + waveN * 64 + ni * 16 + cno;
                Ob[(size_t)gq * 1024 + col] = acc[mi][ni][r] * inv;
            }
        }
    }
}

// ----------------------------- prep kernels (f32 inputs) -------------------
__global__ void k_cast(const float4* __restrict__ in, bf16* __restrict__ out,
                       int n4) {
    int i = blockIdx.x * 256 + threadIdx.x;
    if (i >= n4) return;
    float4 v = in[i];
    bf16x4 o;
    o[0] = (__bf16)v.x; o[1] = (__bf16)v.y; o[2] = (__bf16)v.z; o[3] = (__bf16)v.w;
    *(bf16x4*)(out + 4 * (size_t)i) = o;
}

// out[idx] = in[(idx & mask) * tstride + (idx >> shift)]; n = total elements.
__global__ void k_transpose(const float* __restrict__ in, bf16* __restrict__ out,
                            int n, int mask, int shift, int tstride) {
    int idx = blockIdx.x * 256 + threadIdx.x;
    if (idx >= n) return;
    out[idx] = __float2bfloat16(in[(size_t)(idx & mask) * tstride + (idx >> shift)]);
}

extern "C" void kernel_launch(void* const* d_in, const int* in_sizes, int n_in,
                              void* d_out, int out_size, void* d_ws, size_t ws_size,
                              hipStream_t stream) {
    const int B = 4, N = 4096, E = 1024, D = 256;
    const float* X   = (const float*)d_in[0];  // [4,4096,1024]
    const float* Wq  = (const float*)d_in[1];  // [1024,256]
    const float* Wk  = (const float*)d_in[2];  // [1024,256]
    const float* Wvd = (const float*)d_in[3];  // [1024,256]
    const float* Wvu = (const float*)d_in[4];  // [256,1024]
    float* out = (float*)d_out;                // [4,4096,1024]

    // ---- workspace layout (122 MiB + 64 KiB; P overlays dead Xb/weights) ---
    const long long MiB = 1ll << 20;
    char* ws = (char*)d_ws;
    bf16* Xb     = (bf16*)(ws);                       // [ 0,32)  [16384][1024]
    bf16* WqT    = (bf16*)(ws + 32 * MiB);            // 512 KiB  [256][1024]
    bf16* WkT    = (bf16*)(ws + 32 * MiB + 524288);   // 512 KiB (contiguous!)
    bf16* WvdT   = (bf16*)(ws + 32 * MiB + 1048576);  // 512 KiB (contiguous!)
    bf16* WvupT  = (bf16*)(ws + 32 * MiB + 1572864);  // 512 KiB  [1024][256]
    bf16* P      = (bf16*)(ws);                       // [ 0,66)  packed tri
    bf16* Qm     = (bf16*)(ws + 66 * MiB);            // [66,74)  [16384][256]
    bf16* Km     = (bf16*)(ws + 74 * MiB);            // [74,82)  = Qm+cBatch
    bf16* Vd     = (bf16*)(ws + 82 * MiB);            // [82,90)  = Qm+2*cBatch
    bf16* VT     = (bf16*)(ws + 90 * MiB);            // [90,122) [4][1024][4096]
    float* lsum  = (float*)(ws + 122 * MiB);          // 64 KiB   [4][4096]
    // lifetime: Xb/W*T dead before k_score writes P (alias [0,66) ok)

    const int n4 = B * N * E / 4;
    k_cast<<<(n4 + 255) / 256, 256, 0, stream>>>((const float4*)X, Xb, n4);
    // WqT[d][e] = Wq[e][d]: idx=d*1024+e -> e=idx&1023, d=idx>>10, stride 256
    k_transpose<<<1024, 256, 0, stream>>>(Wq,  WqT,  E * D, 1023, 10, 256);
    k_transpose<<<1024, 256, 0, stream>>>(Wk,  WkT,  E * D, 1023, 10, 256);
    k_transpose<<<1024, 256, 0, stream>>>(Wvd, WvdT, E * D, 1023, 10, 256);
    // WvupT[dv][d] = Wvu[d][dv]: idx=dv*256+d -> d=idx&255, dv=idx>>8, str 1024
    k_transpose<<<1024, 256, 0, stream>>>(Wvu, WvupT, D * E, 255, 8, 1024);
    hipMemsetAsync(lsum, 0, (size_t)B * N * sizeof(float), stream);

    // Q,K,Vd = Xb @ {Wq,Wk,Wvdown}  (z=3: outputs at Qm + z*8MiB)
    k_gemm_plain<<<dim3(D / 128, (B * N) / 128, 3), 256, 0, stream>>>(
        Xb, 0, WqT, (long long)D * E, Qm, (long long)B * N * D,
        E, E, D, E / BK);

    // VT[b][dv][n] = sum_d WvupT[dv][d] * Vd[b][n][d]   (K=256)
    k_gemm_plain<<<dim3(N / 128, E / 128, B), 256, 0, stream>>>(
        WvupT, 0, Vd, (long long)N * D, VT, (long long)E * N,
        D, D, N, D / BK);

    // P~ = exp(mask(Q K^T / 16)) packed; row sums -> lsum (528 tri tiles/b)
    k_score<<<dim3(528, 1, B), 256, 0, stream>>>(Qm, Km, P, lsum);

    // Out = (P~ @ V) / l  (LDS-free, XCD-grouped, CU-coset balanced)
    k_pv<<<dim3(1024, 1, 1), 256, 0, stream>>>(P, VT, lsum, out);
}

// Round 8
// 313.498 us; speedup vs baseline: 1.6400x; 1.6400x over previous
//
#include <hip/hip_runtime.h>
#include <hip/hip_bf16.h>

// DotProductAttention: B=4, N=4096, E=1024, D=256. f32 in/out.
// Pipeline: cast/prep -> QKV GEMM (z=3) -> VT GEMM -> k_score (packed
// lower-tri P~, rowsum l) -> k_pv (O = P~ @ V / l).
// R11 (best, 331us): XCD-grouped k_pv + dbuf vmcnt(4); k_pv 112us, Mfma 27%.
// R12 FAILED: 2-bit XOR swizzle null (structural at 64B rows); DEPTH=3 cut
// residency. R13 FAILED: LDS-free gathers TA-bound (266us).
// R14 (no result, infra): k_pv 8-phase-family rebuild.
// R15 = R14 minus the zero-page (workspace back to R11's 122MiB+64KiB):
// 256x128 tile, BK=64, 512thr/8 waves (4Mx2N, per-wave 64x64 acc[4][4]).
// 3-buf LDS (144KB), stage-2-ahead, ONE barrier + counted vmcnt(6) per
// K-tile (never 0 mid-loop), setprio around MFMA, (row&7)<<4 XOR swizzle
// (conflict-free b128 at 128B rows; impossible at BK=32 -> R12 null).
// Upper-half K-tail (2 tiles beyond pitch K1): waves with waveM<2 own
// A-rows 0..127 exclusively -> wave-uniform skip of ds_read+MFMA at tail
// tiles (exact zero contribution); staging still issues all 6 loads
// (garbage-but-in-bounds P bytes, bounds verified incl. b=3/qt=31) so
// per-wave vmcnt counts stay uniform. qt16-pairs (p,15-p): every block
// exactly 68 K-tiles; l=b*64+dv*8+p -> the 8 dv-siblings sharing the P
// stream share l%8 -> one XCD. k_score/GEMMs: R11 verbatim.

typedef __hip_bfloat16 bf16;
typedef __bf16 bf16x4 __attribute__((ext_vector_type(4)));
typedef __bf16 bf16x8 __attribute__((ext_vector_type(8)));
typedef float f32x4 __attribute__((ext_vector_type(4)));

#define BK 32
#define HALF_BYTES 8192   // 128*BK*2 bytes per LDS buffer half (R11 path)
#define PVBUF 49152       // k_pv: A[256][64] (32KB) + B[128][64] (16KB)

__device__ __forceinline__ void gload_lds16(const bf16* g, bf16* l) {
    __builtin_amdgcn_global_load_lds(
        (const __attribute__((address_space(1))) unsigned int*)g,
        (__attribute__((address_space(3))) unsigned int*)l, 16, 0, 0);
}

__device__ __forceinline__ void zero_acc(f32x4 acc[4][4]) {
#pragma unroll
    for (int mi = 0; mi < 4; ++mi)
#pragma unroll
        for (int ni = 0; ni < 4; ++ni) {
            f32x4 zf = {0.f, 0.f, 0.f, 0.f};
            acc[mi][ni] = zf;
        }
}

// ---------- LDS-staged 128x128 tile (R11, verbatim): dense GEMMs + score ---
__device__ __forceinline__ void mm_tile(const bf16* __restrict__ Ablk,
                                        const bf16* __restrict__ Bblk,
                                        int lda, int ldb, int kiters,
                                        bf16* As, bf16* Bs, f32x4 acc[4][4]) {
    const int tid  = threadIdx.x;
    const int wave = tid >> 6;
    const int lane = tid & 63;

    const int F0 = wave * 2048 + lane * 16;  // byte offset; 4 waves cover 8KB
    const int F1 = F0 + 1024;
    const int r0 = F0 >> 6, c0 = (F0 & 63) >> 1;  // 64B (=32 bf16) per row
    const int r1 = F1 >> 6, c1 = (F1 & 63) >> 1;
    const bf16* ga0 = Ablk + (size_t)r0 * lda + c0;
    const bf16* ga1 = Ablk + (size_t)r1 * lda + c1;
    const bf16* gb0 = Bblk + (size_t)r0 * ldb + c0;
    const bf16* gb1 = Bblk + (size_t)r1 * ldb + c1;

    const int waveM = wave >> 1, waveN = wave & 1;
    const int mrow = waveM * 64 + (lane & 15);
    const int nrow = waveN * 64 + (lane & 15);
    const int koff = (lane >> 4) * 8;

#define STAGE_TO(buf)                                                        \
    {                                                                        \
        char* Ad = (char*)As + (buf) * HALF_BYTES;                           \
        char* Bd = (char*)Bs + (buf) * HALF_BYTES;                           \
        gload_lds16(ga0, (bf16*)(Ad + F0));                                  \
        gload_lds16(ga1, (bf16*)(Ad + F1));                                  \
        gload_lds16(gb0, (bf16*)(Bd + F0));                                  \
        gload_lds16(gb1, (bf16*)(Bd + F1));                                  \
        ga0 += BK; ga1 += BK; gb0 += BK; gb1 += BK;                          \
    }

    STAGE_TO(0);
    int cur = 0;
    for (int it = 0; it < kiters - 1; ++it) {
        const int nxt = cur ^ 1;
        STAGE_TO(nxt);

        __builtin_amdgcn_sched_barrier(0);
        asm volatile("s_waitcnt vmcnt(4)" ::: "memory");
        __builtin_amdgcn_sched_barrier(0);
        __builtin_amdgcn_s_barrier();
        __builtin_amdgcn_sched_barrier(0);

        {
            const bf16* Ar = (const bf16*)((const char*)As + cur * HALF_BYTES);
            const bf16* Br = (const bf16*)((const char*)Bs + cur * HALF_BYTES);
            bf16x8 af[4], bfr[4];
#pragma unroll
            for (int mi = 0; mi < 4; ++mi)
                af[mi] = *(const bf16x8*)(Ar + (mrow + mi * 16) * BK + koff);
#pragma unroll
            for (int ni = 0; ni < 4; ++ni)
                bfr[ni] = *(const bf16x8*)(Br + (nrow + ni * 16) * BK + koff);
#pragma unroll
            for (int mi = 0; mi < 4; ++mi)
#pragma unroll
                for (int ni = 0; ni < 4; ++ni)
                    acc[mi][ni] = __builtin_amdgcn_mfma_f32_16x16x32_bf16(
                        af[mi], bfr[ni], acc[mi][ni], 0, 0, 0);
        }

        __builtin_amdgcn_sched_barrier(0);
        asm volatile("s_waitcnt lgkmcnt(0)" ::: "memory");
        __builtin_amdgcn_sched_barrier(0);
        __builtin_amdgcn_s_barrier();
        __builtin_amdgcn_sched_barrier(0);
        cur = nxt;
    }

    __builtin_amdgcn_sched_barrier(0);
    asm volatile("s_waitcnt vmcnt(0)" ::: "memory");
    __builtin_amdgcn_sched_barrier(0);
    __builtin_amdgcn_s_barrier();
    __builtin_amdgcn_sched_barrier(0);
    {
        const bf16* Ar = (const bf16*)((const char*)As + cur * HALF_BYTES);
        const bf16* Br = (const bf16*)((const char*)Bs + cur * HALF_BYTES);
        bf16x8 af[4], bfr[4];
#pragma unroll
        for (int mi = 0; mi < 4; ++mi)
            af[mi] = *(const bf16x8*)(Ar + (mrow + mi * 16) * BK + koff);
#pragma unroll
        for (int ni = 0; ni < 4; ++ni)
            bfr[ni] = *(const bf16x8*)(Br + (nrow + ni * 16) * BK + koff);
#pragma unroll
        for (int mi = 0; mi < 4; ++mi)
#pragma unroll
            for (int ni = 0; ni < 4; ++ni)
                acc[mi][ni] = __builtin_amdgcn_mfma_f32_16x16x32_bf16(
                    af[mi], bfr[ni], acc[mi][ni], 0, 0, 0);
    }
#undef STAGE_TO
}

// ---------------- plain GEMM: C[m][n] = A*BT^T, bf16 store -----------------
__global__ __launch_bounds__(256, 2) void k_gemm_plain(
    const bf16* __restrict__ A, long long aBatch,
    const bf16* __restrict__ BT, long long bBatch,
    bf16* __restrict__ C, long long cBatch,
    int lda, int ldb, int ldc, int kiters) {
    __shared__ __align__(16) bf16 As[2 * 128 * BK];
    __shared__ __align__(16) bf16 Bs[2 * 128 * BK];
    const int nBase = blockIdx.x * 128;
    const int mBase = blockIdx.y * 128;
    const int z = blockIdx.z;
    const bf16* Ab = A + (size_t)z * aBatch + (size_t)mBase * lda;
    const bf16* Bb = BT + (size_t)z * bBatch + (size_t)nBase * ldb;

    f32x4 acc[4][4];
    zero_acc(acc);
    mm_tile(Ab, Bb, lda, ldb, kiters, As, Bs, acc);

    const int tid = threadIdx.x, wave = tid >> 6, lane = tid & 63;
    const int waveM = wave >> 1, waveN = wave & 1;
    const int quad = lane >> 4, cno = lane & 15;
    bf16* Cb = C + (size_t)z * cBatch;
#pragma unroll
    for (int mi = 0; mi < 4; ++mi) {
        int row0 = mBase + waveM * 64 + mi * 16 + quad * 4;
#pragma unroll
        for (int ni = 0; ni < 4; ++ni) {
            int col = nBase + waveN * 64 + ni * 16 + cno;
#pragma unroll
            for (int r = 0; r < 4; ++r)
                Cb[(size_t)(row0 + r) * ldc + col] = __float2bfloat16(acc[mi][ni][r]);
        }
    }
}

// ---------------- score: packed P~ = exp(mask(Q K^T / 16)) -----------------
// R11 verbatim. 528 lower-tri tiles/batch; P packed: block-row qt starts at
// element 16384*tri(qt), pitch (qt+1)*128. Row sums -> lsum atomics.
#define P_BATCH 8650752ll  // 528 * 16384 elements per batch
__global__ __launch_bounds__(256, 2) void k_score(
    const bf16* __restrict__ Qm, const bf16* __restrict__ Km,
    bf16* __restrict__ P, float* __restrict__ lsum) {
    const int f = blockIdx.x, b = blockIdx.z;
    int qt = (int)((sqrtf(8.f * (float)f + 1.f) - 1.f) * 0.5f);
    while ((qt + 1) * (qt + 2) / 2 <= f) ++qt;
    while (qt * (qt + 1) / 2 > f) --qt;
    const int kt = f - qt * (qt + 1) / 2;

    __shared__ __align__(16) bf16 As[2 * 128 * BK];
    __shared__ __align__(16) bf16 Bs[2 * 128 * BK];

    const bf16* Ab = Qm + ((size_t)b * 4096 + (size_t)qt * 128) * 256;
    const bf16* Bb = Km + ((size_t)b * 4096 + (size_t)kt * 128) * 256;

    f32x4 acc[4][4];
    zero_acc(acc);
    mm_tile(Ab, Bb, 256, 256, 256 / BK, As, Bs, acc);

    const int tid = threadIdx.x, wave = tid >> 6, lane = tid & 63;
    const int waveM = wave >> 1, waveN = wave & 1;
    const int quad = lane >> 4, cno = lane & 15;
    const int pitch = (qt + 1) * 128;
    bf16* Pb = P + b * P_BATCH + (size_t)16384 * (qt * (qt + 1) / 2);
    float* lb = lsum + b * 4096;
#pragma unroll
    for (int mi = 0; mi < 4; ++mi) {
        const int lq0 = waveM * 64 + mi * 16 + quad * 4;
        float rs[4] = {0.f, 0.f, 0.f, 0.f};
#pragma unroll
        for (int ni = 0; ni < 4; ++ni) {
            const int cn = waveN * 64 + ni * 16 + cno;
            const int gk = kt * 128 + cn;
#pragma unroll
            for (int r = 0; r < 4; ++r) {
                const int gq = qt * 128 + lq0 + r;
                float s = acc[mi][ni][r] * 0.0625f;  // 1/sqrt(256)
                // ref quirk: masked OR exactly-zero score -> exp = 0
                float p = (gk <= gq && s != 0.0f) ? __expf(s) : 0.0f;
                bf16 pb = __float2bfloat16(p);
                Pb[(size_t)(lq0 + r) * pitch + gk] = pb;
                rs[r] += __bfloat162float(pb);  // sum what PV multiplies
            }
        }
#pragma unroll
        for (int r = 0; r < 4; ++r) {
            float v = rs[r];
            v += __shfl_xor(v, 1);
            v += __shfl_xor(v, 2);
            v += __shfl_xor(v, 4);
            v += __shfl_xor(v, 8);
            if (cno == 0) atomicAdd(&lb[qt * 128 + lq0 + r], v);
        }
    }
}

// --------------- PV GEMM: 256x128 tile, 8-phase-family schedule ------------
// Grid 256 blocks x 512 thr. l = b*64 + dv*8 + p: pair (p,15-p) -> exactly
// 68 K-tiles/block (uniform); l%8 = p -> the 8 dv-siblings sharing the P
// stream land on one XCD. One barrier + counted vmcnt(6) per K-tile; 3-buf
// LDS stage-2-ahead; (row&7)<<4 XOR swizzle (conflict-free at 128B rows);
// setprio(1) around MFMA clusters. Upper-half K-tail: waveM<2 waves skip
// ds_read+MFMA (exact zero contribution); staging stays uniform.
__global__ __launch_bounds__(512, 2) void k_pv(
    const bf16* __restrict__ Pm, const bf16* __restrict__ VT,
    const float* __restrict__ lsum, float* __restrict__ Out) {
    __shared__ __align__(16) char lds[3 * PVBUF];
    const int l = blockIdx.x;
    const int p = l & 7, dv = (l >> 3) & 7, b = l >> 6;
    const int tid = threadIdx.x;
    const int wave = tid >> 6, lane = tid & 63;
    const int waveM = wave >> 1, waveN = wave & 1;  // 4M x 2N
    const int quad = lane >> 4, cno = lane & 15;

    // staging: 512 thr x 16B = 8KB per segment; 64 rows/segment, 128B rows
    const int srow = tid >> 3;                                  // 0..63
    const int swzEl = (((tid & 7) * 16) ^ ((srow & 7) << 4)) >> 1;
    const int F = tid * 16;

    const bf16* VTb = VT + ((size_t)b * 1024 + dv * 128) * 4096;
    float* Ob = Out + (size_t)b * 4096 * 1024;
    const float* lb = lsum + b * 4096;

    // fragment read offsets (swizzled): row*128B + ((kk*64+quad*16)^rswz)
    const int rswz = (lane & 7) << 4;
    int offA[4], offB[4], colk[2];
#pragma unroll
    for (int mi = 0; mi < 4; ++mi)
        offA[mi] = (waveM * 64 + mi * 16 + (lane & 15)) * 128;
#pragma unroll
    for (int ni = 0; ni < 4; ++ni)
        offB[ni] = (waveN * 64 + ni * 16 + (lane & 15)) * 128;
    colk[0] = (quad * 16) ^ rswz;
    colk[1] = (64 + quad * 16) ^ rswz;

    const int Qv0 = p, Qv1 = 15 - p;
#pragma unroll 1
    for (int c = 0; c < 2; ++c) {
        const int Q = c ? Qv1 : Qv0;
        const int qt0 = 2 * Q;
        const int pitch1 = (qt0 + 1) * 128;   // upper-half P pitch (= K1)
        const int pitch2 = (qt0 + 2) * 128;   // lower-half P pitch (= K2)
        const bf16* base1 = Pm + (size_t)b * P_BATCH
                            + (size_t)16384 * (qt0 * (qt0 + 1) / 2);
        const bf16* base2 = Pm + (size_t)b * P_BATCH
                            + (size_t)16384 * ((qt0 + 1) * (qt0 + 2) / 2);
        const int nt = (qt0 + 2) * 2;         // K-tiles of 64 (>= 4)

        const bf16* a0 = base1 + (size_t)srow * pitch1 + swzEl;
        const bf16* a1 = base1 + (size_t)(64 + srow) * pitch1 + swzEl;
        const bf16* a2 = base2 + (size_t)srow * pitch2 + swzEl;
        const bf16* a3 = base2 + (size_t)(64 + srow) * pitch2 + swzEl;
        const bf16* b0 = VTb + (size_t)srow * 4096 + swzEl;
        const bf16* b1 = VTb + (size_t)(64 + srow) * 4096 + swzEl;

        // protect previous chain's last-tile LDS reads from our staging
        __builtin_amdgcn_s_barrier();

#define STG(bi)                                                              \
    {                                                                        \
        char* Ad = lds + (bi) * PVBUF;                                       \
        char* Bd = Ad + 32768;                                               \
        gload_lds16(a0, (bf16*)(Ad + F));                                    \
        gload_lds16(a1, (bf16*)(Ad + 8192 + F));                             \
        gload_lds16(a2, (bf16*)(Ad + 16384 + F));                            \
        gload_lds16(a3, (bf16*)(Ad + 24576 + F));                            \
        gload_lds16(b0, (bf16*)(Bd + F));                                    \
        gload_lds16(b1, (bf16*)(Bd + 8192 + F));                             \
        a0 += 64; a1 += 64; a2 += 64; a3 += 64; b0 += 64; b1 += 64;          \
    }

        f32x4 acc[4][4];
        zero_acc(acc);
        STG(0);
        STG(1);
        int buf = 0;
        for (int t = 0; t < nt; ++t) {
            __builtin_amdgcn_sched_barrier(0);
            if (t < nt - 1)
                asm volatile("s_waitcnt vmcnt(6)" ::: "memory");
            else
                asm volatile("s_waitcnt vmcnt(0)" ::: "memory");
            __builtin_amdgcn_sched_barrier(0);
            __builtin_amdgcn_s_barrier();
            __builtin_amdgcn_sched_barrier(0);
            if (t + 2 < nt) {
                int bi = buf + 2; if (bi >= 3) bi -= 3;
                STG(bi);
            }
            // upper-half K-tail: waveM<2 (A-rows 0..127) has zero
            // contribution for t >= nt-2 -> wave-uniform skip (exact).
            if (!(waveM < 2 && t >= nt - 2)) {
                const char* Ab = lds + buf * PVBUF;
                const char* Bd = Ab + 32768;
#pragma unroll
                for (int kk = 0; kk < 2; ++kk) {
                    bf16x8 af[4], bfv[4];
#pragma unroll
                    for (int mi = 0; mi < 4; ++mi)
                        af[mi] = *(const bf16x8*)(Ab + offA[mi] + colk[kk]);
#pragma unroll
                    for (int ni = 0; ni < 4; ++ni)
                        bfv[ni] = *(const bf16x8*)(Bd + offB[ni] + colk[kk]);
                    __builtin_amdgcn_s_setprio(1);
#pragma unroll
                    for (int mi = 0; mi < 4; ++mi)
#pragma unroll
                        for (int ni = 0; ni < 4; ++ni)
                            acc[mi][ni] =
                                __builtin_amdgcn_mfma_f32_16x16x32_bf16(
                                    af[mi], bfv[ni], acc[mi][ni], 0, 0, 0);
                    __builtin_amdgcn_s_setprio(0);
                }
            }
            buf = (buf + 1 == 3) ? 0 : buf + 1;
        }
#undef STG

        // epilogue: O[gq, col] = acc / l
#pragma unroll
        for (int mi = 0; mi < 4; ++mi) {
            const int lq0 = waveM * 64 + mi * 16 + quad * 4;
#pragma unroll
            for (int r = 0; r < 4; ++r) {
                const int gq = Q * 256 + lq0 + r;
                const float inv = 1.0f / lb[gq];
#pragma unroll
                for (int ni = 0; ni < 4; ++ni) {
                    const int col = dv * 128 + waveN * 64 + ni * 16 + cno;
                    Ob[(size_t)gq * 1024 + col] = acc[mi][ni][r] * inv;
                }
            }
        }
    }
}

// ----------------------------- prep kernels (f32 inputs) -------------------
__global__ void k_cast(const float4* __restrict__ in, bf16* __restrict__ out,
                       int n4) {
    int i = blockIdx.x * 256 + threadIdx.x;
    if (i >= n4) return;
    float4 v = in[i];
    bf16x4 o;
    o[0] = (__bf16)v.x; o[1] = (__bf16)v.y; o[2] = (__bf16)v.z; o[3] = (__bf16)v.w;
    *(bf16x4*)(out + 4 * (size_t)i) = o;
}

// out[idx] = in[(idx & mask) * tstride + (idx >> shift)]; n = total elements.
__global__ void k_transpose(const float* __restrict__ in, bf16* __restrict__ out,
                            int n, int mask, int shift, int tstride) {
    int idx = blockIdx.x * 256 + threadIdx.x;
    if (idx >= n) return;
    out[idx] = __float2bfloat16(in[(size_t)(idx & mask) * tstride + (idx >> shift)]);
}

extern "C" void kernel_launch(void* const* d_in, const int* in_sizes, int n_in,
                              void* d_out, int out_size, void* d_ws, size_t ws_size,
                              hipStream_t stream) {
    const int B = 4, N = 4096, E = 1024, D = 256;
    const float* X   = (const float*)d_in[0];  // [4,4096,1024]
    const float* Wq  = (const float*)d_in[1];  // [1024,256]
    const float* Wk  = (const float*)d_in[2];  // [1024,256]
    const float* Wvd = (const float*)d_in[3];  // [1024,256]
    const float* Wvu = (const float*)d_in[4];  // [256,1024]
    float* out = (float*)d_out;                // [4,4096,1024]

    // ---- workspace layout (122 MiB + 64 KiB; P overlays dead Xb/weights) ---
    const long long MiB = 1ll << 20;
    char* ws = (char*)d_ws;
    bf16* Xb     = (bf16*)(ws);                       // [ 0,32)  [16384][1024]
    bf16* WqT    = (bf16*)(ws + 32 * MiB);            // 512 KiB  [256][1024]
    bf16* WkT    = (bf16*)(ws + 32 * MiB + 524288);   // 512 KiB (contiguous!)
    bf16* WvdT   = (bf16*)(ws + 32 * MiB + 1048576);  // 512 KiB (contiguous!)
    bf16* WvupT  = (bf16*)(ws + 32 * MiB + 1572864);  // 512 KiB  [1024][256]
    bf16* P      = (bf16*)(ws);                       // [ 0,66)  packed tri
    bf16* Qm     = (bf16*)(ws + 66 * MiB);            // [66,74)  [16384][256]
    bf16* Km     = (bf16*)(ws + 74 * MiB);            // [74,82)  = Qm+cBatch
    bf16* Vd     = (bf16*)(ws + 82 * MiB);            // [82,90)  = Qm+2*cBatch
    bf16* VT     = (bf16*)(ws + 90 * MiB);            // [90,122) [4][1024][4096]
    float* lsum  = (float*)(ws + 122 * MiB);          // 64 KiB   [4][4096]
    // lifetime: Xb/W*T dead before k_score writes P (alias [0,66) ok)

    const int n4 = B * N * E / 4;
    k_cast<<<(n4 + 255) / 256, 256, 0, stream>>>((const float4*)X, Xb, n4);
    // WqT[d][e] = Wq[e][d]: idx=d*1024+e -> e=idx&1023, d=idx>>10, stride 256
    k_transpose<<<1024, 256, 0, stream>>>(Wq,  WqT,  E * D, 1023, 10, 256);
    k_transpose<<<1024, 256, 0, stream>>>(Wk,  WkT,  E * D, 1023, 10, 256);
    k_transpose<<<1024, 256, 0, stream>>>(Wvd, WvdT, E * D, 1023, 10, 256);
    // WvupT[dv][d] = Wvu[d][dv]: idx=dv*256+d -> d=idx&255, dv=idx>>8, str 1024
    k_transpose<<<1024, 256, 0, stream>>>(Wvu, WvupT, D * E, 255, 8, 1024);
    hipMemsetAsync(lsum, 0, (size_t)B * N * sizeof(float), stream);

    // Q,K,Vd = Xb @ {Wq,Wk,Wvdown}  (z=3: outputs at Qm + z*8MiB)
    k_gemm_plain<<<dim3(D / 128, (B * N) / 128, 3), 256, 0, stream>>>(
        Xb, 0, WqT, (long long)D * E, Qm, (long long)B * N * D,
        E, E, D, E / BK);

    // VT[b][dv][n] = sum_d WvupT[dv][d] * Vd[b][n][d]   (K=256)
    k_gemm_plain<<<dim3(N / 128, E / 128, B), 256, 0, stream>>>(
        WvupT, 0, Vd, (long long)N * D, VT, (long long)E * N,
        D, D, N, D / BK);

    // P~ = exp(mask(Q K^T / 16)) packed; row sums -> lsum (528 tri tiles/b)
    k_score<<<dim3(528, 1, B), 256, 0, stream>>>(Qm, Km, P, lsum);

    // Out = (P~ @ V) / l  (256x128 8-phase-family, pair-balanced, XCD-grouped)
    k_pv<<<dim3(256, 1, 1), 512, 0, stream>>>(P, VT, lsum, out);
}